// Round 20
// baseline (424.553 us; speedup 1.0000x reference)
//
#include <hip/hip_runtime.h>
#include <hip/hip_bf16.h>
#include <stdint.h>

#define EPSQ 1e-5f

typedef int i32x4 __attribute__((ext_vector_type(4)));

__device__ inline void gload16(const void* g, void* l){
  __builtin_amdgcn_global_load_lds((const __attribute__((address_space(1))) unsigned int*)g,
                                   (__attribute__((address_space(3))) unsigned int*)l, 16, 0, 0);
}

__device__ inline unsigned pack4(float4 v, float s, float lo, float hi){
  int a = (int)fminf(fmaxf(rintf(v.x*s), lo), hi);
  int b = (int)fminf(fmaxf(rintf(v.y*s), lo), hi);
  int c = (int)fminf(fmaxf(rintf(v.z*s), lo), hi);
  int d = (int)fminf(fmaxf(rintf(v.w*s), lo), hi);
  return (unsigned)((a&255)|((b&255)<<8)|((c&255)<<16)|((d&255)<<24));
}

// ---------------- mean|w| over BOTH weights, one dispatch ----------------
__global__ void absmean2(const float* __restrict__ w1, const float* __restrict__ w2,
                         int n4, double* __restrict__ partial){
  const int half = blockIdx.x >> 10;             // 0: w1, 1: w2
  const float4* w4 = (const float4*)(half ? w2 : w1);
  double s = 0.0;
  int idx = (blockIdx.x & 1023)*blockDim.x + threadIdx.x;
  int stride = 1024*blockDim.x;
  for (int i = idx; i < n4; i += stride){
    float4 v = w4[i];
    s += (double)(fabsf(v.x)+fabsf(v.y)+fabsf(v.z)+fabsf(v.w));
  }
  __shared__ double sm[256];
  sm[threadIdx.x] = s; __syncthreads();
  for (int o=128;o>0;o>>=1){ if (threadIdx.x<o) sm[threadIdx.x]+=sm[threadIdx.x+o]; __syncthreads(); }
  if (threadIdx.x==0) partial[blockIdx.x] = sm[0];
}

__global__ void finalize_scales(const double* __restrict__ partial, float* __restrict__ scalebuf, double inv_n){
  __shared__ double sm[256];
  int t = threadIdx.x;
  double s1 = partial[t] + partial[t+256] + partial[t+512] + partial[t+768];
  sm[t]=s1; __syncthreads();
  for(int o=128;o>0;o>>=1){ if(t<o) sm[t]+=sm[t+o]; __syncthreads(); }
  double m1 = sm[0];
  __syncthreads();
  double s2 = partial[1024+t]+partial[1280+t]+partial[1536+t]+partial[1792+t];
  sm[t]=s2; __syncthreads();
  for(int o=128;o>0;o>>=1){ if(t<o) sm[t]+=sm[t+o]; __syncthreads(); }
  if (t==0){
    scalebuf[0] = 1.0f / fmaxf((float)(m1*inv_n),    EPSQ);   // s_w1
    scalebuf[1] = 1.0f / fmaxf((float)(sm[0]*inv_n), EPSQ);   // s_w2
  }
}

// ---------------- ternary weight quantization -> int8 {-1,0,1} ----------------
__global__ void wquant8(const float* __restrict__ w, char* __restrict__ wq,
                        const float* __restrict__ scalebuf, int which){
  int i = blockIdx.x*256 + threadIdx.x;
  float s = scalebuf[which];
  const float4* w4 = (const float4*)w;
  float4 v0 = w4[(size_t)i*4], v1 = w4[(size_t)i*4+1], v2 = w4[(size_t)i*4+2], v3 = w4[(size_t)i*4+3];
  uint4 pk = make_uint4(pack4(v0,s,-1.f,1.f), pack4(v1,s,-1.f,1.f),
                        pack4(v2,s,-1.f,1.f), pack4(v3,s,-1.f,1.f));
  *reinterpret_cast<uint4*>(wq + (size_t)i*16) = pk;
}

// ---------------- per-token activation quant -> int8 + scale + rowMax=0 ----------------
__global__ void aquant8c(const float* __restrict__ x, char* __restrict__ xq,
                         float* __restrict__ s_a, int* __restrict__ rowMax){
  int m = blockIdx.x, t = threadIdx.x;           // 256 thr, D=2048
  if (t==0) rowMax[m] = 0;
  const float4* x4 = (const float4*)(x + (size_t)m*2048);
  float4 a = x4[t*2], b = x4[t*2+1];
  float va[8] = {a.x,a.y,a.z,a.w,b.x,b.y,b.z,b.w};
  float mx = 0.f;
  #pragma unroll
  for (int j=0;j<8;j++) mx = fmaxf(mx, fabsf(va[j]));
  #pragma unroll
  for (int o=1;o<64;o<<=1) mx = fmaxf(mx, __shfl_xor(mx, o, 64));
  __shared__ float wm[4];
  if ((t&63)==0) wm[t>>6] = mx;
  __syncthreads();
  mx = fmaxf(fmaxf(wm[0],wm[1]), fmaxf(wm[2],wm[3]));
  float s = 127.f / fmaxf(mx, EPSQ);
  if (t==0) s_a[m] = s;
  uint2 pk = make_uint2(pack4(a,s,-128.f,127.f), pack4(b,s,-128.f,127.f));
  *reinterpret_cast<uint2*>(xq + (size_t)m*2048 + t*8) = pk;
}

// ---------------- 128x128 i8 GEMM, 2 FAT waves (64x128 each), ring-2, 2 blocks/CU ----------------
// Retile: 2 waves/block (128 thr), wave tile 64x128 -> acc[4][8]; MFMA:ds_read ratio
// 2.0 -> 2.67 (48 reads/block/step vs 64), LDS floor 1536->1152 cyc/CU < MFMA 1306 ->
// MFMA-bound. 1 wave/SIMD: each k-half's 32-MFMA cluster (~650 cyc) self-hides the next
// k-half's 12 ds_reads; compiler schedules reads/waitcnts (plain loads - no rule-18
// hazard). launch_bounds(128,1): VGPR budget 512, no spill of the ~250-reg working set.
// Same LDS layout/swizzle/ring-2/grids as R14-R19. setprio around MFMA; vmcnt(0)+barrier
// once per step.
// EPI 0: h16 = min(relu,65535), per-row max -> rowMax. EPI 1: out f32 = acc * inv2(row).
template<int EPI, int STEPS>
__global__ __launch_bounds__(128,1) void gemmK(
    const char* __restrict__ A, const char* __restrict__ B, void* __restrict__ Cv,
    int moff, int* __restrict__ rowMax, const float* __restrict__ s_a,
    const float* __restrict__ scalebuf)
{
  const int Ks = STEPS << 7;
  __shared__ __align__(16) char sm[2*32768 + 1024];
  int* smax = (int*)(sm + 2*32768);
  const int tid = threadIdx.x, lane = tid & 63;
  const int wr = tid >> 6;                        // 2 waves: rows wr*64..wr*64+63, all 128 cols
  const int n0 = blockIdx.x*128, m0 = blockIdx.y*128;

  i32x4 acc[4][8] = {};

  // staging: 128 threads cover 128 rows x 128B for A and B; thread t: chunk col t&7,
  // rows (t>>3) + i*16 (i=0..7); row&7 = (t>>3)&7 invariant -> per-thread constant swizzle.
  const int trow = tid >> 3;
  const int scl  = (tid & 7) ^ (trow & 7);
  const char* gA = A + (size_t)(m0 + trow)*Ks + scl*16;
  const char* gB = B + (size_t)(n0 + trow)*Ks + scl*16;

  auto stage = [&](int sbase, int kt){            // 16 gload16/thread
    #pragma unroll
    for (int i=0;i<8;i++)
      gload16(gA + kt + (size_t)(i*16)*Ks, sm + sbase + (i*128+tid)*16);
    #pragma unroll
    for (int i=0;i<8;i++)
      gload16(gB + kt + (size_t)(i*16)*Ks, sm + sbase + 16384 + (i*128+tid)*16);
  };

  // read-side offsets (XOR swizzle: logical chunk ^ (row&7))
  const int frow = lane & 15, kb = lane >> 4;
  int aoff[2][4], boff[2][8];
  #pragma unroll
  for (int kh=0;kh<2;kh++){
    #pragma unroll
    for (int f=0;f<4;f++){
      int ra = wr*64 + f*16 + frow;
      aoff[kh][f] = ra*128 + ((((kh<<2)|kb) ^ (ra&7))<<4);
    }
    #pragma unroll
    for (int f=0;f<8;f++){
      int rb = f*16 + frow;
      boff[kh][f] = 16384 + rb*128 + ((((kh<<2)|kb) ^ (rb&7))<<4);
    }
  }

  auto kstep = [&](const int slot, int t, const int mode){  // mode 0: stage t+1; 2: last
    const char* base = sm + slot*32768;
    if (mode == 0) stage((slot^1)*32768, (t+1)<<7);
    #pragma unroll
    for (int kh=0;kh<2;kh++){
      i32x4 av[4], bv[8];
      #pragma unroll
      for (int f=0;f<4;f++) av[f] = *reinterpret_cast<const i32x4*>(base + aoff[kh][f]);
      #pragma unroll
      for (int f=0;f<8;f++) bv[f] = *reinterpret_cast<const i32x4*>(base + boff[kh][f]);
      __builtin_amdgcn_s_setprio(1);
      #pragma unroll
      for (int fm=0;fm<4;fm++)
        #pragma unroll
        for (int fn=0;fn<8;fn++)
          acc[fm][fn] = __builtin_amdgcn_mfma_i32_16x16x64_i8(av[fm], bv[fn], acc[fm][fn], 0,0,0);
      __builtin_amdgcn_s_setprio(0);
    }
    if (mode == 0) asm volatile("s_waitcnt vmcnt(0)" ::: "memory");  // t+1 landed (issued early)
    if (mode != 2) __builtin_amdgcn_s_barrier();
  };

  stage(0, 0);
  asm volatile("s_waitcnt vmcnt(0)" ::: "memory");
  __builtin_amdgcn_s_barrier();
  __builtin_amdgcn_sched_barrier(0);

  for (int tt = 0; tt < STEPS/2 - 1; ++tt){
    int t = tt*2;
    kstep(0, t,   0);
    kstep(1, t+1, 0);
  }
  kstep(0, STEPS-2, 0);
  kstep(1, STEPS-1, 2);

  // ---- epilogue ----
  const int cc = lane & 15, cr = (lane >> 4)*4;
  if (EPI == 0){
    __syncthreads();
    smax[tid] = 0;                                 // 128 threads cover 128 rows
    __syncthreads();
    ushort* C16 = (ushort*)Cv;
    #pragma unroll
    for (int fm=0;fm<4;fm++){
      #pragma unroll
      for (int reg=0;reg<4;reg++){
        int rl = wr*64 + fm*16 + cr + reg;
        size_t r = (size_t)(m0 + rl);
        int rmax = 0;
        #pragma unroll
        for (int fn=0;fn<8;fn++){
          int v = acc[fm][fn][reg]; v = v > 0 ? v : 0;       // fused relu, exact int
          C16[r*8192 + n0 + fn*16 + cc] = (ushort)(v > 65535 ? 65535 : v);
          rmax = v > rmax ? v : rmax;
        }
        atomicMax(&smax[rl], rmax);
      }
    }
    __syncthreads();
    atomicMax(&rowMax[m0 + tid], smax[tid]);
  } else {
    float* out = (float*)Cv;
    float sw1 = scalebuf[0], sw2 = scalebuf[1];
    #pragma unroll
    for (int fm=0;fm<4;fm++){
      #pragma unroll
      for (int reg=0;reg<4;reg++){
        int rl = wr*64 + fm*16 + cr + reg;
        size_t r = (size_t)(moff + m0 + rl);
        int Mi = rowMax[r];
        float maxref = (float)Mi / (s_a[r]*sw1);
        float inv2 = fmaxf(maxref, EPSQ) / (127.f*sw2);
        #pragma unroll
        for (int fn=0;fn<8;fn++)
          out[r*2048 + n0 + fn*16 + cc] = (float)acc[fm][fn][reg] * inv2;
      }
    }
  }
}

// ---------------- h16 -> int8 requant (rq = 127/Mi, exact integer domain) ----------------
__global__ void hquant(const ushort* __restrict__ h16, char* __restrict__ hq,
                       const int* __restrict__ rowMax){
  int m = blockIdx.y;
  int Mi = rowMax[m];
  float rqv = (Mi > 0) ? 127.f/(float)Mi : 0.f;
  size_t base = (size_t)m*8192 + blockIdx.x*2048 + threadIdx.x*8;
  uint4 pk = *reinterpret_cast<const uint4*>(h16 + base);
  unsigned u[4] = {pk.x, pk.y, pk.z, pk.w};
  unsigned o[2] = {0,0};
  #pragma unroll
  for (int j=0;j<8;j++){
    float h = (float)(u[j>>1] >> ((j&1)*16) & 0xffff);
    int q = (int)fminf(rintf(h*rqv), 127.f);            // h >= 0
    o[j>>2] |= (unsigned)(q & 255) << ((j&3)*8);
  }
  *reinterpret_cast<uint2*>(hq + base) = make_uint2(o[0], o[1]);
}

extern "C" void kernel_launch(void* const* d_in, const int* in_sizes, int n_in,
                              void* d_out, int out_size, void* d_ws, size_t ws_size,
                              hipStream_t stream){
  const float* x  = (const float*)d_in[0];
  const float* w1 = (const float*)d_in[1];
  const float* w2 = (const float*)d_in[2];
  float* out = (float*)d_out;

  const int MTOK = 8192, Mc = 1024;
  const size_t nW = (size_t)8192*2048;   // 16 MiB int8 per weight

  char* ws = (char*)d_ws; size_t off = 0;
  auto alloc = [&](size_t n)->char*{ char* p = ws+off; off = (off+n+255) & ~(size_t)255; return p; };

  float*  s_a     = (float*)alloc((size_t)MTOK*4);
  int*    rowMax  = (int*)  alloc((size_t)MTOK*4);
  float*  scalebuf= (float*)alloc(256);
  double* partial = (double*)alloc(2048*8);
  char*   w1q     = alloc(nW);

  // Tiered layout (ws evidence: >=100.7MB usable, <102.6MB total)
  bool sepW2=false, fullA=false; int hqM=4096;
  char *w2q=nullptr, *a8=nullptr, *a8c=nullptr, *hq=nullptr;
  ushort* h16=nullptr;
  if (off + 5*nW + 4096 <= ws_size){                 // plan A
    sepW2 = true; fullA = true;
    w2q = alloc(nW);
    h16 = (ushort*)alloc(nW);
    a8  = alloc(nW);
    hq  = alloc(2*nW);
  } else if (off + 4*nW + 4096 <= ws_size){          // plan B
    fullA = true;
    h16 = (ushort*)alloc(nW); w2q = (char*)h16;      // aliased: re-quantized per segment
    a8  = alloc(nW);
    hq  = alloc(2*nW);
  } else {                                           // plan C
    h16 = (ushort*)alloc(nW); w2q = (char*)h16;
    a8c = alloc((size_t)Mc*2048);
    hqM = 0;
    for (int m = 4096; m >= 1024; m >>= 1)
      if (off + (size_t)m*8192 <= ws_size){ hqM = m; break; }
    if (!hqM) return;
    hq = alloc((size_t)hqM*8192);
  }

  absmean2<<<2048,256,0,stream>>>(w1, w2, (int)(nW/4), partial);
  finalize_scales<<<1,256,0,stream>>>(partial, scalebuf, 1.0/(double)nW);
  wquant8<<<(int)(nW/16/256),256,0,stream>>>(w1, w1q, scalebuf, 0);
  if (sepW2) wquant8<<<(int)(nW/16/256),256,0,stream>>>(w2, w2q, scalebuf, 1);
  if (fullA) aquant8c<<<MTOK,256,0,stream>>>(x, a8, s_a, rowMax);

  for (int s = 0; s < MTOK/hqM; ++s){
    for (int c = 0; c < hqM/Mc; ++c){
      int ch = s*hqM + c*Mc;
      const char* aptr;
      if (fullA) aptr = a8 + (size_t)ch*2048;
      else {
        aquant8c<<<Mc,256,0,stream>>>(x + (size_t)ch*2048, a8c, s_a + ch, rowMax + ch);
        aptr = a8c;
      }
      gemmK<0,16><<<dim3(64, Mc/128),128,0,stream>>>(
          aptr, w1q, h16, 0, rowMax + ch, nullptr, scalebuf);
      hquant<<<dim3(4, Mc),256,0,stream>>>(h16, hq + (size_t)c*Mc*8192, rowMax + ch);
    }
    if (!sepW2)  // h16 region dead for this segment -> quantize w2 into it
      wquant8<<<(int)(nW/16/256),256,0,stream>>>(w2, w2q, scalebuf, 1);
    gemmK<1,64><<<dim3(16, hqM/128),128,0,stream>>>(
        hq, w2q, out, s*hqM, rowMax, s_a, scalebuf);
  }
}

// Round 21
// 363.709 us; speedup vs baseline: 1.1673x; 1.1673x over previous
//
#include <hip/hip_runtime.h>
#include <hip/hip_bf16.h>
#include <stdint.h>

#define EPSQ 1e-5f

typedef int i32x4 __attribute__((ext_vector_type(4)));

__device__ inline void gload16(const void* g, void* l){
  __builtin_amdgcn_global_load_lds((const __attribute__((address_space(1))) unsigned int*)g,
                                   (__attribute__((address_space(3))) unsigned int*)l, 16, 0, 0);
}

__device__ inline unsigned pack4(float4 v, float s, float lo, float hi){
  int a = (int)fminf(fmaxf(rintf(v.x*s), lo), hi);
  int b = (int)fminf(fmaxf(rintf(v.y*s), lo), hi);
  int c = (int)fminf(fmaxf(rintf(v.z*s), lo), hi);
  int d = (int)fminf(fmaxf(rintf(v.w*s), lo), hi);
  return (unsigned)((a&255)|((b&255)<<8)|((c&255)<<16)|((d&255)<<24));
}

// ---------------- mean|w| over BOTH weights, one dispatch ----------------
__global__ void absmean2(const float* __restrict__ w1, const float* __restrict__ w2,
                         int n4, double* __restrict__ partial){
  const int half = blockIdx.x >> 10;             // 0: w1, 1: w2
  const float4* w4 = (const float4*)(half ? w2 : w1);
  double s = 0.0;
  int idx = (blockIdx.x & 1023)*blockDim.x + threadIdx.x;
  int stride = 1024*blockDim.x;
  for (int i = idx; i < n4; i += stride){
    float4 v = w4[i];
    s += (double)(fabsf(v.x)+fabsf(v.y)+fabsf(v.z)+fabsf(v.w));
  }
  __shared__ double sm[256];
  sm[threadIdx.x] = s; __syncthreads();
  for (int o=128;o>0;o>>=1){ if (threadIdx.x<o) sm[threadIdx.x]+=sm[threadIdx.x+o]; __syncthreads(); }
  if (threadIdx.x==0) partial[blockIdx.x] = sm[0];
}

__global__ void finalize_scales(const double* __restrict__ partial, float* __restrict__ scalebuf, double inv_n){
  __shared__ double sm[256];
  int t = threadIdx.x;
  double s1 = partial[t] + partial[t+256] + partial[t+512] + partial[t+768];
  sm[t]=s1; __syncthreads();
  for(int o=128;o>0;o>>=1){ if(t<o) sm[t]+=sm[t+o]; __syncthreads(); }
  double m1 = sm[0];
  __syncthreads();
  double s2 = partial[1024+t]+partial[1280+t]+partial[1536+t]+partial[1792+t];
  sm[t]=s2; __syncthreads();
  for(int o=128;o>0;o>>=1){ if(t<o) sm[t]+=sm[t+o]; __syncthreads(); }
  if (t==0){
    scalebuf[0] = 1.0f / fmaxf((float)(m1*inv_n),    EPSQ);   // s_w1
    scalebuf[1] = 1.0f / fmaxf((float)(sm[0]*inv_n), EPSQ);   // s_w2
  }
}

// ---------------- ternary weight quantization -> int8 {-1,0,1} ----------------
__global__ void wquant8(const float* __restrict__ w, char* __restrict__ wq,
                        const float* __restrict__ scalebuf, int which){
  int i = blockIdx.x*256 + threadIdx.x;
  float s = scalebuf[which];
  const float4* w4 = (const float4*)w;
  float4 v0 = w4[(size_t)i*4], v1 = w4[(size_t)i*4+1], v2 = w4[(size_t)i*4+2], v3 = w4[(size_t)i*4+3];
  uint4 pk = make_uint4(pack4(v0,s,-1.f,1.f), pack4(v1,s,-1.f,1.f),
                        pack4(v2,s,-1.f,1.f), pack4(v3,s,-1.f,1.f));
  *reinterpret_cast<uint4*>(wq + (size_t)i*16) = pk;
}

// ---------------- per-token activation quant -> int8 + scale + rowMax=0 ----------------
__global__ void aquant8c(const float* __restrict__ x, char* __restrict__ xq,
                         float* __restrict__ s_a, int* __restrict__ rowMax){
  int m = blockIdx.x, t = threadIdx.x;           // 256 thr, D=2048
  if (t==0) rowMax[m] = 0;
  const float4* x4 = (const float4*)(x + (size_t)m*2048);
  float4 a = x4[t*2], b = x4[t*2+1];
  float va[8] = {a.x,a.y,a.z,a.w,b.x,b.y,b.z,b.w};
  float mx = 0.f;
  #pragma unroll
  for (int j=0;j<8;j++) mx = fmaxf(mx, fabsf(va[j]));
  #pragma unroll
  for (int o=1;o<64;o<<=1) mx = fmaxf(mx, __shfl_xor(mx, o, 64));
  __shared__ float wm[4];
  if ((t&63)==0) wm[t>>6] = mx;
  __syncthreads();
  mx = fmaxf(fmaxf(wm[0],wm[1]), fmaxf(wm[2],wm[3]));
  float s = 127.f / fmaxf(mx, EPSQ);
  if (t==0) s_a[m] = s;
  uint2 pk = make_uint2(pack4(a,s,-128.f,127.f), pack4(b,s,-128.f,127.f));
  *reinterpret_cast<uint2*>(xq + (size_t)m*2048 + t*8) = pk;
}

// ---------------- GEMM1: 256x256 i8, 8 FAT waves (64x128), ring-2, 2 waves/SIMD ----------------
// Waves tiled 4M x 2N of 64x128 -> 12 ds_read + 32 MFMA per k-half (ratio 2.67 vs 2.0).
// LDS slot = [A 256x128B | B 256x128B] = 64KB, ring-2 = 128KB -> 1 block/CU but 8 waves
// = 2 waves/SIMD (fixes R20's 1-wave/SIMD latency exposure). Floor: LDS 2304 cyc/step
// < MFMA 2611 cyc/SIMD -> MFMA-bound. K=2048, 16 steps, grid 32 x (Mc/256) = 256 blocks.
// Epilogue: h16 = min(relu,65535) + per-row max -> rowMax.
__global__ __launch_bounds__(512,2) void gemm1_256(
    const char* __restrict__ A, const char* __restrict__ B, ushort* __restrict__ C16,
    int* __restrict__ rowMax)
{
  constexpr int STEPS = 16;
  const int Ks = 2048;
  __shared__ __align__(16) char sm[2*65536 + 1024];
  int* smax = (int*)(sm + 2*65536);
  const int tid = threadIdx.x, lane = tid & 63, w = tid >> 6;
  const int wr = w >> 1, wc = w & 1;              // 4M x 2N waves of 64x128
  const int n0 = blockIdx.x*256, m0 = blockIdx.y*256;

  i32x4 acc[4][8] = {};

  // staging: chunk p = i*512+tid -> row = i*64+(tid>>3) (0..255), col = tid&7;
  // row&7 = (tid>>3)&7 invariant across i -> per-thread constant pre-swizzle.
  const int trow = tid >> 3;
  const int scl  = (tid & 7) ^ (trow & 7);
  const char* gA = A + (size_t)(m0 + trow)*Ks + scl*16;
  const char* gB = B + (size_t)(n0 + trow)*Ks + scl*16;

  auto stage = [&](int sbase, int kt){            // 8 gload16/thread
    #pragma unroll
    for (int i=0;i<4;i++)
      gload16(gA + kt + (size_t)(i*64)*Ks, sm + sbase + (i*512+tid)*16);
    #pragma unroll
    for (int i=0;i<4;i++)
      gload16(gB + kt + (size_t)(i*64)*Ks, sm + sbase + 32768 + (i*512+tid)*16);
  };

  // read-side offsets (XOR swizzle: logical chunk ^ (row&7))
  const int frow = lane & 15, kb = lane >> 4;
  int aoff[2][4], boff[2][8];
  #pragma unroll
  for (int kh=0;kh<2;kh++){
    #pragma unroll
    for (int f=0;f<4;f++){
      int ra = wr*64 + f*16 + frow;
      aoff[kh][f] = ra*128 + ((((kh<<2)|kb) ^ (ra&7))<<4);
    }
    #pragma unroll
    for (int f=0;f<8;f++){
      int rb = wc*128 + f*16 + frow;
      boff[kh][f] = 32768 + rb*128 + ((((kh<<2)|kb) ^ (rb&7))<<4);
    }
  }

  auto kstep = [&](const int slot, int t, const int mode){  // mode 0: stage t+1; 2: last
    const char* base = sm + slot*65536;
    if (mode == 0) stage((slot^1)*65536, (t+1)<<7);
    #pragma unroll
    for (int kh=0;kh<2;kh++){
      i32x4 av[4], bv[8];
      #pragma unroll
      for (int f=0;f<4;f++) av[f] = *reinterpret_cast<const i32x4*>(base + aoff[kh][f]);
      #pragma unroll
      for (int f=0;f<8;f++) bv[f] = *reinterpret_cast<const i32x4*>(base + boff[kh][f]);
      __builtin_amdgcn_s_setprio(1);
      #pragma unroll
      for (int fm=0;fm<4;fm++)
        #pragma unroll
        for (int fn=0;fn<8;fn++)
          acc[fm][fn] = __builtin_amdgcn_mfma_i32_16x16x64_i8(av[fm], bv[fn], acc[fm][fn], 0,0,0);
      __builtin_amdgcn_s_setprio(0);
    }
    if (mode == 0) asm volatile("s_waitcnt vmcnt(0)" ::: "memory");  // t+1 landed (issued early)
    if (mode != 2) __builtin_amdgcn_s_barrier();
  };

  stage(0, 0);
  asm volatile("s_waitcnt vmcnt(0)" ::: "memory");
  __builtin_amdgcn_s_barrier();
  __builtin_amdgcn_sched_barrier(0);

  for (int tt = 0; tt < STEPS/2 - 1; ++tt){
    int t = tt*2;
    kstep(0, t,   0);
    kstep(1, t+1, 0);
  }
  kstep(0, STEPS-2, 0);
  kstep(1, STEPS-1, 2);

  // ---- epilogue: relu + clamp store + per-row max ----
  const int cc = lane & 15, cr = (lane >> 4)*4;
  __syncthreads();
  if (tid < 256) smax[tid] = 0;
  __syncthreads();
  #pragma unroll
  for (int fm=0;fm<4;fm++){
    #pragma unroll
    for (int reg=0;reg<4;reg++){
      int rl = wr*64 + fm*16 + cr + reg;
      size_t r = (size_t)(m0 + rl);
      int rmax = 0;
      #pragma unroll
      for (int fn=0;fn<8;fn++){
        int v = acc[fm][fn][reg]; v = v > 0 ? v : 0;        // fused relu, exact int
        C16[r*8192 + n0 + wc*128 + fn*16 + cc] = (ushort)(v > 65535 ? 65535 : v);
        rmax = v > rmax ? v : rmax;
      }
      atomicMax(&smax[rl], rmax);
    }
  }
  __syncthreads();
  if (tid < 256) atomicMax(&rowMax[m0 + tid], smax[tid]);
}

// ---------------- 128x128 i8 GEMM (R19 verbatim), used for GEMM2 + plan-C GEMM1 ----------------
template<int EPI, int STEPS>
__global__ __launch_bounds__(256,2) void gemmK(
    const char* __restrict__ A, const char* __restrict__ B, void* __restrict__ Cv,
    int moff, int* __restrict__ rowMax, const float* __restrict__ s_a,
    const float* __restrict__ scalebuf)
{
  const int Ks = STEPS << 7;
  __shared__ __align__(16) char sm[2*32768 + 1024];
  int* smax = (int*)(sm + 2*32768);
  const int tid = threadIdx.x, lane = tid & 63, w = tid >> 6;
  const int wr = w >> 1, wc = w & 1;               // 2M x 2N waves, 64x64 each
  const int n0 = blockIdx.x*128, m0 = blockIdx.y*128;

  i32x4 acc[4][4] = {};

  const int trow = tid >> 3;
  const int scl  = (tid & 7) ^ (trow & 7);
  const char* gA = A + (size_t)(m0 + trow)*Ks + scl*16;
  const char* gB = B + (size_t)(n0 + trow)*Ks + scl*16;

  auto stage = [&](int sbase, int kt){             // 8 gload16/thread
    #pragma unroll
    for (int i=0;i<4;i++){
      gload16(gA + kt + (size_t)(i*32)*Ks, sm + sbase + (i*256+tid)*16);
      gload16(gB + kt + (size_t)(i*32)*Ks, sm + sbase + 16384 + (i*256+tid)*16);
    }
  };

  const int frow = lane & 15, kb = lane >> 4;
  int aoff[2][4], boff[2][4];
  #pragma unroll
  for (int kh=0;kh<2;kh++){
    #pragma unroll
    for (int f=0;f<4;f++){
      int ra = wr*64 + f*16 + frow;
      aoff[kh][f] = ra*128 + ((((kh<<2)|kb) ^ (ra&7))<<4);
      int rb = wc*64 + f*16 + frow;
      boff[kh][f] = 16384 + rb*128 + ((((kh<<2)|kb) ^ (rb&7))<<4);
    }
  }

  auto kstep = [&](const int slot, int t, const int mode){  // mode 0: stage t+1; 2: last
    const char* base = sm + slot*32768;
    i32x4 av0[4], bv0[4], av1[4], bv1[4];
    #pragma unroll
    for (int f=0;f<4;f++){
      av0[f] = *reinterpret_cast<const i32x4*>(base + aoff[0][f]);
      bv0[f] = *reinterpret_cast<const i32x4*>(base + boff[0][f]);
    }
    #pragma unroll
    for (int f=0;f<4;f++){
      av1[f] = *reinterpret_cast<const i32x4*>(base + aoff[1][f]);
      bv1[f] = *reinterpret_cast<const i32x4*>(base + boff[1][f]);
    }
    if (mode == 0) stage((slot^1)*32768, (t+1)<<7);
    asm volatile("s_waitcnt lgkmcnt(8)" ::: "memory");   // phase-0 operands landed
    __builtin_amdgcn_sched_barrier(0);
    __builtin_amdgcn_s_setprio(1);
    #pragma unroll
    for (int fm=0;fm<4;fm++)
      #pragma unroll
      for (int fn=0;fn<4;fn++)
        acc[fm][fn] = __builtin_amdgcn_mfma_i32_16x16x64_i8(av0[fm], bv0[fn], acc[fm][fn], 0,0,0);
    __builtin_amdgcn_s_setprio(0);
    asm volatile("s_waitcnt lgkmcnt(0)" ::: "memory");   // phase-1 (hidden under MFMA)
    __builtin_amdgcn_sched_barrier(0);
    __builtin_amdgcn_s_setprio(1);
    #pragma unroll
    for (int fm=0;fm<4;fm++)
      #pragma unroll
      for (int fn=0;fn<4;fn++)
        acc[fm][fn] = __builtin_amdgcn_mfma_i32_16x16x64_i8(av1[fm], bv1[fn], acc[fm][fn], 0,0,0);
    __builtin_amdgcn_s_setprio(0);
    if (mode == 0) asm volatile("s_waitcnt vmcnt(0)" ::: "memory");  // t+1 landed (issued early)
    if (mode != 2) __builtin_amdgcn_s_barrier();
  };

  stage(0, 0);
  asm volatile("s_waitcnt vmcnt(0)" ::: "memory");
  __builtin_amdgcn_s_barrier();
  __builtin_amdgcn_sched_barrier(0);

  for (int tt = 0; tt < STEPS/2 - 1; ++tt){
    int t = tt*2;
    kstep(0, t,   0);
    kstep(1, t+1, 0);
  }
  kstep(0, STEPS-2, 0);
  kstep(1, STEPS-1, 2);

  // ---- epilogue ----
  const int cc = lane & 15, cr = (lane >> 4)*4;
  if (EPI == 0){
    __syncthreads();
    if (tid < 128) smax[tid] = 0;
    __syncthreads();
    ushort* C16 = (ushort*)Cv;
    #pragma unroll
    for (int fm=0;fm<4;fm++){
      #pragma unroll
      for (int reg=0;reg<4;reg++){
        int rl = wr*64 + fm*16 + cr + reg;
        size_t r = (size_t)(m0 + rl);
        int rmax = 0;
        #pragma unroll
        for (int fn=0;fn<4;fn++){
          int v = acc[fm][fn][reg]; v = v > 0 ? v : 0;       // fused relu, exact int
          C16[r*8192 + n0 + wc*64 + fn*16 + cc] = (ushort)(v > 65535 ? 65535 : v);
          rmax = v > rmax ? v : rmax;
        }
        atomicMax(&smax[rl], rmax);
      }
    }
    __syncthreads();
    if (tid < 128) atomicMax(&rowMax[m0 + tid], smax[tid]);
  } else {
    float* out = (float*)Cv;
    float sw1 = scalebuf[0], sw2 = scalebuf[1];
    #pragma unroll
    for (int fm=0;fm<4;fm++){
      #pragma unroll
      for (int reg=0;reg<4;reg++){
        int rl = wr*64 + fm*16 + cr + reg;
        size_t r = (size_t)(moff + m0 + rl);
        int Mi = rowMax[r];
        float maxref = (float)Mi / (s_a[r]*sw1);
        float inv2 = fmaxf(maxref, EPSQ) / (127.f*sw2);
        #pragma unroll
        for (int fn=0;fn<4;fn++)
          out[r*2048 + n0 + wc*64 + fn*16 + cc] = (float)acc[fm][fn][reg] * inv2;
      }
    }
  }
}

// ---------------- h16 -> int8 requant (rq = 127/Mi, exact integer domain) ----------------
__global__ void hquant(const ushort* __restrict__ h16, char* __restrict__ hq,
                       const int* __restrict__ rowMax){
  int m = blockIdx.y;
  int Mi = rowMax[m];
  float rqv = (Mi > 0) ? 127.f/(float)Mi : 0.f;
  size_t base = (size_t)m*8192 + blockIdx.x*2048 + threadIdx.x*8;
  uint4 pk = *reinterpret_cast<const uint4*>(h16 + base);
  unsigned u[4] = {pk.x, pk.y, pk.z, pk.w};
  unsigned o[2] = {0,0};
  #pragma unroll
  for (int j=0;j<8;j++){
    float h = (float)(u[j>>1] >> ((j&1)*16) & 0xffff);
    int q = (int)fminf(rintf(h*rqv), 127.f);            // h >= 0
    o[j>>2] |= (unsigned)(q & 255) << ((j&3)*8);
  }
  *reinterpret_cast<uint2*>(hq + base) = make_uint2(o[0], o[1]);
}

extern "C" void kernel_launch(void* const* d_in, const int* in_sizes, int n_in,
                              void* d_out, int out_size, void* d_ws, size_t ws_size,
                              hipStream_t stream){
  const float* x  = (const float*)d_in[0];
  const float* w1 = (const float*)d_in[1];
  const float* w2 = (const float*)d_in[2];
  float* out = (float*)d_out;

  const int MTOK = 8192;
  const size_t nW = (size_t)8192*2048;   // 16 MiB int8 per weight

  char* ws = (char*)d_ws; size_t off = 0;
  auto alloc = [&](size_t n)->char*{ char* p = ws+off; off = (off+n+255) & ~(size_t)255; return p; };

  float*  s_a     = (float*)alloc((size_t)MTOK*4);
  int*    rowMax  = (int*)  alloc((size_t)MTOK*4);
  float*  scalebuf= (float*)alloc(256);
  double* partial = (double*)alloc(2048*8);
  char*   w1q     = alloc(nW);

  // Plan NEW (needs ~96.6 MB): w2q aliased into 32MB h16 (Mc=2048), full a8, hqM=4096.
  // Plan C fallback (R19): aliased 16MB h16, chunked a8, adaptive hqM, 128^2 GEMM1.
  bool big = false;
  char *w2q=nullptr, *a8=nullptr, *hq=nullptr;
  ushort* h16=nullptr;
  int hqM = 4096, Mc = 2048;
  if (off + 2*nW /*h16*/ + nW /*a8*/ + 2*nW /*hq*/ + 4096 <= ws_size){
    big = true;
    h16 = (ushort*)alloc(2*nW);                    // 32MB (Mc=2048 x 8192 u16)
    w2q = (char*)h16;                              // aliased; re-quantized per segment
    a8  = alloc(nW);
    hq  = alloc(2*nW);
  } else {
    Mc = 1024;
    h16 = (ushort*)alloc(nW); w2q = (char*)h16;
    a8  = alloc((size_t)Mc*2048);
    hqM = 0;
    for (int m = 4096; m >= 1024; m >>= 1)
      if (off + (size_t)m*8192 <= ws_size){ hqM = m; break; }
    if (!hqM) return;
    hq = alloc((size_t)hqM*8192);
  }

  absmean2<<<2048,256,0,stream>>>(w1, w2, (int)(nW/4), partial);
  finalize_scales<<<1,256,0,stream>>>(partial, scalebuf, 1.0/(double)nW);
  wquant8<<<(int)(nW/16/256),256,0,stream>>>(w1, w1q, scalebuf, 0);
  if (big) aquant8c<<<MTOK,256,0,stream>>>(x, a8, s_a, rowMax);

  for (int s = 0; s < MTOK/hqM; ++s){
    for (int c = 0; c < hqM/Mc; ++c){
      int ch = s*hqM + c*Mc;
      if (big){
        gemm1_256<<<dim3(32, Mc/256),512,0,stream>>>(
            a8 + (size_t)ch*2048, w1q, h16, rowMax + ch);
      } else {
        aquant8c<<<Mc,256,0,stream>>>(x + (size_t)ch*2048, a8, s_a + ch, rowMax + ch);
        gemmK<0,16><<<dim3(64, Mc/128),256,0,stream>>>(
            a8, w1q, h16, 0, rowMax + ch, nullptr, scalebuf);
      }
      hquant<<<dim3(4, Mc),256,0,stream>>>(h16, hq + (size_t)c*Mc*8192, rowMax + ch);
    }
    // h16 region dead for this segment -> quantize w2 into it
    wquant8<<<(int)(nW/16/256),256,0,stream>>>(w2, w2q, scalebuf, 1);
    gemmK<1,64><<<dim3(16, hqM/128),256,0,stream>>>(
        hq, w2q, out, s*hqM, rowMax, s_a, scalebuf);
  }
}